// Round 3
// baseline (349.209 us; speedup 1.0000x reference)
//
#include <hip/hip_runtime.h>

typedef __attribute__((ext_vector_type(8))) short short8;
typedef __attribute__((ext_vector_type(8))) unsigned short ushort8;
typedef __attribute__((ext_vector_type(4))) float f32x4;

__device__ __forceinline__ unsigned short f2bf(float f) {
  unsigned int u = __float_as_uint(f);
  u += 0x7fffu + ((u >> 16) & 1u);   // round-to-nearest-even
  return (unsigned short)(u >> 16);
}
__device__ __forceinline__ float bf2f(unsigned short u) {
  return __uint_as_float(((unsigned int)u) << 16);
}
__device__ __forceinline__ void gl_lds16(const void* g, void* l) {
  __builtin_amdgcn_global_load_lds(
      (const __attribute__((address_space(1))) unsigned int*)g,
      (__attribute__((address_space(3))) unsigned int*)l, 16, 0, 0);
}

// ---- prep: W1T2 [256 n'][256 k] bf16 (n'<128: W1a cols, n'>=128: W1b cols),
// ----       W1cT [128 n][32 k] bf16 (edge_attr weight, transposed)
__global__ void prep_weights(const float* __restrict__ W1,
                             unsigned short* __restrict__ W1T2,
                             unsigned short* __restrict__ W1cT) {
  int idx = blockIdx.x * 256 + threadIdx.x;
  if (idx < 65536) {
    int np = idx >> 8, k = idx & 255;
    W1T2[idx] = f2bf(W1[(size_t)(k + ((np >> 7) << 8)) * 128 + (np & 127)]);
  } else if (idx < 65536 + 4096) {
    int j = idx - 65536;
    int n = j >> 5, k = j & 31;
    W1cT[j] = f2bf(W1[(size_t)(512 + k) * 128 + n]);
  }
}

// ---- node projection, single pass: 128 nodes x 256 cols per block.
// ---- Ps[node][256] bf16; within each 128-half, swizzled c' = (c&15)*8 + (c>>4)
__global__ __launch_bounds__(256, 2) void node_proj(
    const float* __restrict__ z, const unsigned short* __restrict__ W1T2,
    unsigned short* __restrict__ Ps, int NN) {
  __shared__ unsigned short As[2][128 * 32];   // 8 KB each
  __shared__ unsigned short Bs[2][256 * 32];   // 16 KB each
  const int tid = threadIdx.x, wid = tid >> 6, lane = tid & 63;
  const int wrow = wid >> 1, wcol = wid & 1;
  const int quad = lane >> 4, l15 = lane & 15;
  const int lrow = lane >> 2, lch = lane & 3;
  const int bm = blockIdx.x;

  const float* zsrc[2];
  int rr[2];
#pragma unroll
  for (int j = 0; j < 2; ++j) {
    rr[j] = (2 * wid + j) * 16 + lrow;
    int node = min(bm * 128 + rr[j], NN - 1);
    zsrc[j] = z + (size_t)node * 256;
  }

  f32x4 acc[4][8] = {};

  auto stage = [&](int ks, int bb) {
    // B tile: 256 rows x 32 k, async, 4 chunks/thread
#pragma unroll
    for (int j = 0; j < 4; ++j) {
      int nb = 4 * wid + j;
      gl_lds16(W1T2 + (size_t)(nb * 16 + lrow) * 256 + ks * 32 + lch * 8,
               &Bs[bb][nb * 512]);
    }
    // A tile: f32 -> bf16 inline
#pragma unroll
    for (int j = 0; j < 2; ++j) {
      const float* g = zsrc[j] + ks * 32 + lch * 8;
      f32x4 a = *(const f32x4*)g;
      f32x4 c = *(const f32x4*)(g + 4);
      ushort8 o;
      o[0]=f2bf(a[0]); o[1]=f2bf(a[1]); o[2]=f2bf(a[2]); o[3]=f2bf(a[3]);
      o[4]=f2bf(c[0]); o[5]=f2bf(c[1]); o[6]=f2bf(c[2]); o[7]=f2bf(c[3]);
      *(ushort8*)&As[bb][rr[j] * 32 + lch * 8] = o;
    }
  };

  auto compute = [&](int bb) {
    short8 af[4], bfv[8];
#pragma unroll
    for (int i = 0; i < 4; ++i)
      af[i] = *(const short8*)&As[bb][(wrow * 64 + i * 16 + l15) * 32 + quad * 8];
#pragma unroll
    for (int i = 0; i < 8; ++i)
      bfv[i] = *(const short8*)&Bs[bb][(wcol * 128 + i * 16 + l15) * 32 + quad * 8];
#pragma unroll
    for (int mi = 0; mi < 4; ++mi)
#pragma unroll
      for (int ni = 0; ni < 8; ++ni)
        acc[mi][ni] = __builtin_amdgcn_mfma_f32_16x16x32_bf16(af[mi], bfv[ni], acc[mi][ni], 0, 0, 0);
  };

  stage(0, 0);
#pragma unroll 1
  for (int s = 0; s < 8; ++s) {
    __syncthreads();
    if (s + 1 < 8) stage(s + 1, (s + 1) & 1);
    compute(s & 1);
  }

  // store: col C = wcol*128 + ni*16 + l15 -> Ps[node][wcol*128 + l15*8 + ni]
  // => per (mi,r) one contiguous ushort8 (16 B) store
#pragma unroll
  for (int mi = 0; mi < 4; ++mi) {
#pragma unroll
    for (int r = 0; r < 4; ++r) {
      int row = wrow * 64 + mi * 16 + quad * 4 + r;
      int node = bm * 128 + row;
      if (node < NN) {
        ushort8 o;
#pragma unroll
        for (int ni = 0; ni < 8; ++ni) o[ni] = f2bf(acc[mi][ni][r]);
        *(ushort8*)&Ps[(size_t)node * 256 + wcol * 128 + l15 * 8] = o;
      }
    }
  }
}

// ---- edge kernel: out[e] = relu(P1[src] + P2[dst] + ea@W1c + b1) . W2 + b2
__global__ __launch_bounds__(256, 3) void edge_pred(
    const int* __restrict__ eidx, const float* __restrict__ ea,
    const unsigned short* __restrict__ Ps, const unsigned short* __restrict__ W1cT,
    const float* __restrict__ b1, const float* __restrict__ W2,
    const float* __restrict__ b2, float* __restrict__ out, int E) {
  __shared__ unsigned short EaS[128 * 32];
  __shared__ unsigned short WcS[128 * 32];
  const int tid = threadIdx.x, wid = tid >> 6, lane = tid & 63;
  const int quad = lane >> 4, l15 = lane & 15;
  const int lrow = lane >> 2, lch = lane & 3;
  const int be = blockIdx.x * 128;

  // 1) eidx loads first — longest dependency chain (eidx -> gather -> acc)
  int srcn[8], dstn[8];
#pragma unroll
  for (int t = 0; t < 8; ++t) {
    int ec = min(be + wid * 32 + (t >> 2) * 16 + quad * 4 + (t & 3), E - 1);
    srcn[t] = eidx[ec];
    dstn[t] = eidx[E + ec];
  }

  // 2) ea loads (independent, issued while eidx in flight)
  const int e_loc = tid >> 1, part = tid & 1;
  const float* gea = ea + (size_t)min(be + e_loc, E - 1) * 32 + part * 16;
  f32x4 va = *(const f32x4*)gea;
  f32x4 vb = *(const f32x4*)(gea + 4);
  f32x4 vc = *(const f32x4*)(gea + 8);
  f32x4 vd = *(const f32x4*)(gea + 12);

  // 3) W1c staging (async)
#pragma unroll
  for (int j = 0; j < 2; ++j) {
    int nb = 2 * wid + j;
    gl_lds16(W1cT + (size_t)(nb * 16 + lrow) * 32 + lch * 8, &WcS[nb * 512]);
  }

  // 4) P gathers — issue as soon as eidx lands
  short8 p1[8], p2[8];
#pragma unroll
  for (int t = 0; t < 8; ++t) {
    p1[t] = *(const short8*)&Ps[(size_t)srcn[t] * 256 + l15 * 8];
    p2[t] = *(const short8*)&Ps[(size_t)dstn[t] * 256 + 128 + l15 * 8];
  }

  // 5) convert + store ea while gathers are in flight
  {
    ushort8 o1, o2;
    o1[0]=f2bf(va[0]); o1[1]=f2bf(va[1]); o1[2]=f2bf(va[2]); o1[3]=f2bf(va[3]);
    o1[4]=f2bf(vb[0]); o1[5]=f2bf(vb[1]); o1[6]=f2bf(vb[2]); o1[7]=f2bf(vb[3]);
    o2[0]=f2bf(vc[0]); o2[1]=f2bf(vc[1]); o2[2]=f2bf(vc[2]); o2[3]=f2bf(vc[3]);
    o2[4]=f2bf(vd[0]); o2[5]=f2bf(vd[1]); o2[6]=f2bf(vd[2]); o2[7]=f2bf(vd[3]);
    *(ushort8*)&EaS[e_loc * 32 + part * 16] = o1;
    *(ushort8*)&EaS[e_loc * 32 + part * 16 + 8] = o2;
  }

  // 6) consume gathers into accumulator BEFORE MFMA (frees landing regs,
  //    forces early gather issue; latency hidden by steps 3/5 + barrier)
  f32x4 acc[2][8];
#pragma unroll
  for (int mi = 0; mi < 2; ++mi)
#pragma unroll
    for (int r = 0; r < 4; ++r) {
      int t = mi * 4 + r;
#pragma unroll
      for (int ni = 0; ni < 8; ++ni)
        acc[mi][ni][r] = bf2f((unsigned short)p1[t][ni]) + bf2f((unsigned short)p2[t][ni]);
    }

  __syncthreads();

  short8 af[2], bfv[8];
#pragma unroll
  for (int mi = 0; mi < 2; ++mi)
    af[mi] = *(const short8*)&EaS[(wid * 32 + mi * 16 + l15) * 32 + quad * 8];
#pragma unroll
  for (int ni = 0; ni < 8; ++ni)
    bfv[ni] = *(const short8*)&WcS[(ni * 16 + l15) * 32 + quad * 8];

#pragma unroll
  for (int mi = 0; mi < 2; ++mi)
#pragma unroll
    for (int ni = 0; ni < 8; ++ni)
      acc[mi][ni] = __builtin_amdgcn_mfma_f32_16x16x32_bf16(af[mi], bfv[ni], acc[mi][ni], 0, 0, 0);

  float b1v[8], w2v[8];
#pragma unroll
  for (int ni = 0; ni < 8; ++ni) {
    int c = ni * 16 + l15;
    b1v[ni] = b1[c];
    w2v[ni] = W2[c];
  }
  const float b2v = b2[0];

#pragma unroll
  for (int mi = 0; mi < 2; ++mi) {
#pragma unroll
    for (int r = 0; r < 4; ++r) {
      float p = 0.f;
#pragma unroll
      for (int ni = 0; ni < 8; ++ni) {
        float h = acc[mi][ni][r] + b1v[ni];
        h = fmaxf(h, 0.f);
        p = fmaf(h, w2v[ni], p);
      }
      p += __shfl_xor(p, 1);
      p += __shfl_xor(p, 2);
      p += __shfl_xor(p, 4);
      p += __shfl_xor(p, 8);
      int e = be + wid * 32 + mi * 16 + quad * 4 + r;
      if (l15 == 0 && e < E) out[e] = p + b2v;
    }
  }
}

extern "C" void kernel_launch(void* const* d_in, const int* in_sizes, int n_in,
                              void* d_out, int out_size, void* d_ws, size_t ws_size,
                              hipStream_t stream) {
  const float* z   = (const float*)d_in[0];
  const int*   eix = (const int*)d_in[1];
  const float* ea  = (const float*)d_in[2];
  const float* W1  = (const float*)d_in[3];
  const float* b1  = (const float*)d_in[4];
  const float* W2  = (const float*)d_in[5];
  const float* b2  = (const float*)d_in[6];
  float* out = (float*)d_out;

  const int E  = in_sizes[1] / 2;     // edge_label_index is [2, E]
  const int NN = in_sizes[0] / 256;   // nodes

  unsigned short* wsp = (unsigned short*)d_ws;
  unsigned short* Ps   = wsp;                               // NN*256 bf16 (51.2 MB)
  unsigned short* W1T2 = wsp + (size_t)NN * 256;            // 256*256 bf16
  unsigned short* W1cT = W1T2 + 65536;                      // 128*32 bf16

  prep_weights<<<273, 256, 0, stream>>>(W1, W1T2, W1cT);

  int nbm = (NN + 127) / 128;
  node_proj<<<nbm, 256, 0, stream>>>(z, W1T2, Ps, NN);

  int ge = (E + 127) / 128;
  edge_pred<<<ge, 256, 0, stream>>>(eix, ea, Ps, W1cT, b1, W2, b2, out, E);
}

// Round 4
// 336.355 us; speedup vs baseline: 1.0382x; 1.0382x over previous
//
#include <hip/hip_runtime.h>

typedef __attribute__((ext_vector_type(8))) short short8;
typedef __attribute__((ext_vector_type(8))) unsigned short ushort8;
typedef __attribute__((ext_vector_type(4))) float f32x4;

__device__ __forceinline__ unsigned short f2bf(float f) {
  unsigned int u = __float_as_uint(f);
  u += 0x7fffu + ((u >> 16) & 1u);   // round-to-nearest-even
  return (unsigned short)(u >> 16);
}
__device__ __forceinline__ float bf2f(unsigned short u) {
  return __uint_as_float(((unsigned int)u) << 16);
}
__device__ __forceinline__ void gl_lds16(const void* g, void* l) {
  __builtin_amdgcn_global_load_lds(
      (const __attribute__((address_space(1))) unsigned int*)g,
      (__attribute__((address_space(3))) unsigned int*)l, 16, 0, 0);
}

// ---- prep: W1T2 [256 n'][256 k] bf16 (n'<128: W1a cols, n'>=128: W1b cols),
// ----       W1cT [128 n][32 k] bf16 (edge_attr weight, transposed)
__global__ void prep_weights(const float* __restrict__ W1,
                             unsigned short* __restrict__ W1T2,
                             unsigned short* __restrict__ W1cT) {
  int idx = blockIdx.x * 256 + threadIdx.x;
  if (idx < 65536) {
    int np = idx >> 8, k = idx & 255;
    W1T2[idx] = f2bf(W1[(size_t)(k + ((np >> 7) << 8)) * 128 + (np & 127)]);
  } else if (idx < 65536 + 4096) {
    int j = idx - 65536;
    int n = j >> 5, k = j & 31;
    W1cT[j] = f2bf(W1[(size_t)(512 + k) * 128 + n]);
  }
}

// ---- node projection, single pass: 128 nodes x 256 cols per block.
// ---- Ps[node][256] bf16; within each 128-half, swizzled c' = (c&15)*8 + (c>>4)
__global__ __launch_bounds__(256, 2) void node_proj(
    const float* __restrict__ z, const unsigned short* __restrict__ W1T2,
    unsigned short* __restrict__ Ps, int NN) {
  __shared__ unsigned short As[2][128 * 32];   // 8 KB each
  __shared__ unsigned short Bs[2][256 * 32];   // 16 KB each
  const int tid = threadIdx.x, wid = tid >> 6, lane = tid & 63;
  const int wrow = wid >> 1, wcol = wid & 1;
  const int quad = lane >> 4, l15 = lane & 15;
  const int lrow = lane >> 2, lch = lane & 3;
  const int bm = blockIdx.x;

  const float* zsrc[2];
  int rr[2];
#pragma unroll
  for (int j = 0; j < 2; ++j) {
    rr[j] = (2 * wid + j) * 16 + lrow;
    int node = min(bm * 128 + rr[j], NN - 1);
    zsrc[j] = z + (size_t)node * 256;
  }

  f32x4 acc[4][8] = {};

  auto stage = [&](int ks, int bb) {
#pragma unroll
    for (int j = 0; j < 4; ++j) {
      int nb = 4 * wid + j;
      gl_lds16(W1T2 + (size_t)(nb * 16 + lrow) * 256 + ks * 32 + lch * 8,
               &Bs[bb][nb * 512]);
    }
#pragma unroll
    for (int j = 0; j < 2; ++j) {
      const float* g = zsrc[j] + ks * 32 + lch * 8;
      f32x4 a = *(const f32x4*)g;
      f32x4 c = *(const f32x4*)(g + 4);
      ushort8 o;
      o[0]=f2bf(a[0]); o[1]=f2bf(a[1]); o[2]=f2bf(a[2]); o[3]=f2bf(a[3]);
      o[4]=f2bf(c[0]); o[5]=f2bf(c[1]); o[6]=f2bf(c[2]); o[7]=f2bf(c[3]);
      *(ushort8*)&As[bb][rr[j] * 32 + lch * 8] = o;
    }
  };

  auto compute = [&](int bb) {
    short8 af[4], bfv[8];
#pragma unroll
    for (int i = 0; i < 4; ++i)
      af[i] = *(const short8*)&As[bb][(wrow * 64 + i * 16 + l15) * 32 + quad * 8];
#pragma unroll
    for (int i = 0; i < 8; ++i)
      bfv[i] = *(const short8*)&Bs[bb][(wcol * 128 + i * 16 + l15) * 32 + quad * 8];
#pragma unroll
    for (int mi = 0; mi < 4; ++mi)
#pragma unroll
      for (int ni = 0; ni < 8; ++ni)
        acc[mi][ni] = __builtin_amdgcn_mfma_f32_16x16x32_bf16(af[mi], bfv[ni], acc[mi][ni], 0, 0, 0);
  };

  stage(0, 0);
#pragma unroll 1
  for (int s = 0; s < 8; ++s) {
    __syncthreads();
    if (s + 1 < 8) stage(s + 1, (s + 1) & 1);
    compute(s & 1);
  }

  // store: col C = wcol*128 + ni*16 + l15 -> Ps[node][wcol*128 + l15*8 + ni]
#pragma unroll
  for (int mi = 0; mi < 4; ++mi) {
#pragma unroll
    for (int r = 0; r < 4; ++r) {
      int row = wrow * 64 + mi * 16 + quad * 4 + r;
      int node = bm * 128 + row;
      if (node < NN) {
        ushort8 o;
#pragma unroll
        for (int ni = 0; ni < 8; ++ni) o[ni] = f2bf(acc[mi][ni][r]);
        *(ushort8*)&Ps[(size_t)node * 256 + wcol * 128 + l15 * 8] = o;
      }
    }
  }
}

// ---- edge kernel, NO LDS / NO barrier:
// ---- out[e] = relu(P1[src] + P2[dst] + ea@W1c + b1) . W2 + b2
__global__ __launch_bounds__(256, 3) void edge_pred(
    const int* __restrict__ eidx, const float* __restrict__ ea,
    const unsigned short* __restrict__ Ps, const unsigned short* __restrict__ W1cT,
    const float* __restrict__ b1, const float* __restrict__ W2,
    const float* __restrict__ b2, float* __restrict__ out, int E) {
  const int tid = threadIdx.x, wid = tid >> 6, lane = tid & 63;
  const int quad = lane >> 4, l15 = lane & 15;
  const int ebase = blockIdx.x * 128 + wid * 32;

  // 1) eidx first — longest dep chain (eidx -> gather -> epilogue)
  int srcn[8], dstn[8];
#pragma unroll
  for (int t = 0; t < 8; ++t) {
    int ec = min(ebase + (t >> 2) * 16 + quad * 4 + (t & 3), E - 1);
    srcn[t] = eidx[ec];
    dstn[t] = eidx[E + ec];
  }

  // 2) ea direct fragment loads (non-temporal: streamed once, keep L2 for Ps).
  //    A-frag: edge = ebase + mi*16 + l15, k = quad*8 + j  -> 64 lanes cover
  //    16 fully-used 128B lines per mi.
  f32x4 ealo[2], eahi[2];
#pragma unroll
  for (int mi = 0; mi < 2; ++mi) {
    const float* g = ea + (size_t)min(ebase + mi * 16 + l15, E - 1) * 32 + quad * 8;
    ealo[mi] = __builtin_nontemporal_load((const f32x4*)g);
    eahi[mi] = __builtin_nontemporal_load((const f32x4*)(g + 4));
  }

  // 3) W1c B-fragments direct from global (8 KB, L2-resident)
  short8 bfv[8];
#pragma unroll
  for (int ni = 0; ni < 8; ++ni)
    bfv[ni] = *(const short8*)&W1cT[(ni * 16 + l15) * 32 + quad * 8];

  // 4) epilogue constants early (off the critical tail)
  float b1v[8], w2v[8];
#pragma unroll
  for (int ni = 0; ni < 8; ++ni) {
    int c = ni * 16 + l15;
    b1v[ni] = b1[c];
    w2v[ni] = W2[c];
  }
  const float b2v = b2[0];

  // 5) P gathers (swizzled rows: 16B contiguous per lane)
  short8 p1[8], p2[8];
#pragma unroll
  for (int t = 0; t < 8; ++t) {
    p1[t] = *(const short8*)&Ps[(size_t)srcn[t] * 256 + l15 * 8];
    p2[t] = *(const short8*)&Ps[(size_t)dstn[t] * 256 + 128 + l15 * 8];
  }

  // 6) convert ea -> A-fragments
  short8 af[2];
#pragma unroll
  for (int mi = 0; mi < 2; ++mi) {
    ushort8 o;
    o[0]=f2bf(ealo[mi][0]); o[1]=f2bf(ealo[mi][1]); o[2]=f2bf(ealo[mi][2]); o[3]=f2bf(ealo[mi][3]);
    o[4]=f2bf(eahi[mi][0]); o[5]=f2bf(eahi[mi][1]); o[6]=f2bf(eahi[mi][2]); o[7]=f2bf(eahi[mi][3]);
    af[mi] = (short8)o;
  }

  // 7) MFMA (depends only on ea + Wc; gathers still in flight)
  f32x4 acc[2][8] = {};
#pragma unroll
  for (int mi = 0; mi < 2; ++mi)
#pragma unroll
    for (int ni = 0; ni < 8; ++ni)
      acc[mi][ni] = __builtin_amdgcn_mfma_f32_16x16x32_bf16(af[mi], bfv[ni], acc[mi][ni], 0, 0, 0);

  // 8) epilogue: consume gathers (latency now fully elapsed)
#pragma unroll
  for (int mi = 0; mi < 2; ++mi) {
#pragma unroll
    for (int r = 0; r < 4; ++r) {
      int t = mi * 4 + r;
      float p = 0.f;
#pragma unroll
      for (int ni = 0; ni < 8; ++ni) {
        float s = bf2f((unsigned short)p1[t][ni]) + bf2f((unsigned short)p2[t][ni]);
        float h = acc[mi][ni][r] + s + b1v[ni];
        h = fmaxf(h, 0.f);
        p = fmaf(h, w2v[ni], p);
      }
      p += __shfl_xor(p, 1);
      p += __shfl_xor(p, 2);
      p += __shfl_xor(p, 4);
      p += __shfl_xor(p, 8);
      int e = ebase + mi * 16 + quad * 4 + r;
      if (l15 == 0 && e < E) out[e] = p + b2v;
    }
  }
}

extern "C" void kernel_launch(void* const* d_in, const int* in_sizes, int n_in,
                              void* d_out, int out_size, void* d_ws, size_t ws_size,
                              hipStream_t stream) {
  const float* z   = (const float*)d_in[0];
  const int*   eix = (const int*)d_in[1];
  const float* ea  = (const float*)d_in[2];
  const float* W1  = (const float*)d_in[3];
  const float* b1  = (const float*)d_in[4];
  const float* W2  = (const float*)d_in[5];
  const float* b2  = (const float*)d_in[6];
  float* out = (float*)d_out;

  const int E  = in_sizes[1] / 2;     // edge_label_index is [2, E]
  const int NN = in_sizes[0] / 256;   // nodes

  unsigned short* wsp = (unsigned short*)d_ws;
  unsigned short* Ps   = wsp;                               // NN*256 bf16 (51.2 MB)
  unsigned short* W1T2 = wsp + (size_t)NN * 256;            // 256*256 bf16
  unsigned short* W1cT = W1T2 + 65536;                      // 128*32 bf16

  prep_weights<<<273, 256, 0, stream>>>(W1, W1T2, W1cT);

  int nbm = (NN + 127) / 128;
  node_proj<<<nbm, 256, 0, stream>>>(z, W1T2, Ps, NN);

  int ge = (E + 127) / 128;
  edge_pred<<<ge, 256, 0, stream>>>(eix, ea, Ps, W1cT, b1, W2, b2, out, E);
}